// Round 6
// baseline (377.988 us; speedup 1.0000x reference)
//
#include <hip/hip_runtime.h>
#include <math.h>

#define BL 16384
#define D  512
#define K  4096
#define NCH 16          // chunks: 512 k / 32 k-per-chunk; per chunk-row: 8 granules x 16 B

// ---- ws layout (bytes) ----
#define OFF_C2    0                // 4096 f
#define OFF_X2    (16<<10)         // 16384 f (aliased as loss partials after rescore)
#define OFF_CNT   (80<<10)         // 4096 f
#define OFF_AVGC  (96<<10)         // 4096 f
#define OFF_SCAL  (112<<10)        // N float @+8
#define OFF_IDX16 (116<<10)        // 16384 u16
#define OFF_KEYS  (160<<10)        // 16384 u64
#define OFF_CAND  (288<<10)        // 16384*8 u16
#define OFF_CBP   (576<<10)        // cb' 16*4096*128 B = 8.39 MB; cbn (8 MB) reuses after argmin
#define OFF_CBN_FB (256<<10)       // fallback cbn

typedef __bf16 bf16x8 __attribute__((ext_vector_type(8)));
typedef float  f32x4  __attribute__((ext_vector_type(4)));
#define MFMA(a,b,c) __builtin_amdgcn_mfma_f32_16x16x32_bf16(a,b,c,0,0,0)

// ================= bit-exact helpers (feed exact rescore — DO NOT TOUCH) ====

__global__ void rowsq_all(const float* __restrict__ x, const float* __restrict__ cb,
                          float* __restrict__ x2, float* __restrict__ c2)
{
    int b    = blockIdx.x;
    int lane = threadIdx.x;              // 64
    const float* p; float* o; int row;
    if (b < K) { p = cb; o = c2; row = b; }
    else       { p = x;  o = x2; row = b - K; }
    p += (size_t)row * D;
    float s = 0.f;
#pragma unroll
    for (int j = 0; j < D / 64; ++j) {
        float v = p[lane + j * 64];
        s = fmaf(v, v, s);
    }
#pragma unroll
    for (int off = 32; off > 0; off >>= 1)
        s += __shfl_down(s, off, 64);
    if (lane == 0) o[row] = s;
}

// exact rescore, bit-identical arithmetic to round-1 (sequential fmaf k=0..511);
// now also emits counts + compact u16 indices (folds old count_kernel).
__global__ __launch_bounds__(256) void rescore_kernel(
    const float* __restrict__ x, const float* __restrict__ cb,
    const float* __restrict__ x2, const float* __restrict__ c2,
    const unsigned short* __restrict__ cand,
    unsigned long long* __restrict__ keys,
    float* __restrict__ counts, unsigned short* __restrict__ idx16)
{
    int t = blockIdx.x * 256 + threadIdx.x;  // 131072
    int row = t >> 3, ci = t & 7;
    int idx = cand[(size_t)row * 8 + ci];
    const float* xp = x  + (size_t)row * D;
    const float* cp = cb + (size_t)idx * D;
    float acc = 0.f;
#pragma unroll 4
    for (int k0 = 0; k0 < D; k0 += 4) {
        float4 xv = *(const float4*)(xp + k0);
        float4 cv = *(const float4*)(cp + k0);
        acc = fmaf(xv.x, cv.x, acc);
        acc = fmaf(xv.y, cv.y, acc);
        acc = fmaf(xv.z, cv.z, acc);
        acc = fmaf(xv.w, cv.w, acc);
    }
    float wv = x2[row] - 2.0f * acc;
    float dd = wv + c2[idx];
    unsigned long long key =
        ((unsigned long long)__float_as_uint(dd) << 12) | (unsigned long long)idx;
#pragma unroll
    for (int m = 1; m < 8; m <<= 1) {
        unsigned long long o = __shfl_xor(key, m, 64);
        key = o < key ? o : key;
    }
    if ((t & 7) == 0) {
        keys[row] = key;
        int kf = (int)(key & 0xFFFULL);
        idx16[row] = (unsigned short)kf;
        atomicAdd(&counts[kf], 1.0f);
    }
}

// ================= primary path ============================================

__device__ __forceinline__ unsigned short f2bf_rne(float f) {
    unsigned u = __float_as_uint(f);
    unsigned r = u + 0x7FFFu + ((u >> 16) & 1u);
    return (unsigned short)(r >> 16);
}

__device__ __forceinline__ void load_lds16(const unsigned short* g, unsigned short* l) {
    __builtin_amdgcn_global_load_lds(
        (const __attribute__((address_space(1))) unsigned int*)(g),
        (__attribute__((address_space(3))) unsigned int*)(l), 16, 0, 0);
}

// fp32 -> hi/lo bf16 granule streams (identical to R5 — proven).
__global__ __launch_bounds__(256) void split_interleave(
    const float* __restrict__ x, const float* __restrict__ cb,
    unsigned short* __restrict__ xp, unsigned short* __restrict__ cbp)
{
    int gw   = blockIdx.x * 4 + (threadIdx.x >> 6);  // global wave id, 0..40959
    int lane = threadIdx.x & 63;
    int rl   = lane >> 3;
    int p    = lane & 7;
    const float* src; unsigned short* dst; int nr, c, r0;
    if (gw < 32768) { c = gw >> 11; r0 = (gw & 2047) * 8; src = x;  dst = xp;  nr = BL; }
    else { int lw = gw - 32768; c = lw >> 9; r0 = (lw & 511) * 8; src = cb; dst = cbp; nr = K; }
    int r = r0 + rl;
    int j = p ^ rl;
    int u = j >> 1, e = j & 1;
    const float* sp = src + (size_t)r * D + c * 32 + u * 8;
    float4 f0 = *(const float4*)sp, f1 = *(const float4*)(sp + 4);
    float f[8] = {f0.x,f0.y,f0.z,f0.w,f1.x,f1.y,f1.z,f1.w};
    __align__(16) unsigned short o[8];
#pragma unroll
    for (int i = 0; i < 8; ++i) {
        unsigned short h = f2bf_rne(f[i]);
        if (e == 0) o[i] = h;
        else {
            float hf = __uint_as_float((unsigned)h << 16);
            o[i] = f2bf_rne(f[i] - hf);
        }
    }
    size_t off = (size_t)(c * nr + r) * 64 + (size_t)p * 8;
    *(uint4*)(dst + off) = *(const uint4*)o;
}

// MFMA approx distance + per-split top-2.  v3:
// Block 128 rows x 256 codes, 4 waves (2x2), wave tile 64x128 = 4x8 of 16x16x32.
// Per chunk (32 k): 24 ds_read_b128 feed 96 MFMAs -> 2x barrier amortization vs R5.
// Top-2 state compressed: v1/v2 f32[16] + u16 idx packed in 8 u32 (40 VGPR).
__global__ __launch_bounds__(256, 2) void argmin_mfma(
    const unsigned short* __restrict__ xp, const unsigned short* __restrict__ cbp,
    const float* __restrict__ x2, const float* __restrict__ c2,
    unsigned short* __restrict__ cand)
{
    __shared__ __align__(16) unsigned short sA[128 * 64];   // 16 KiB
    __shared__ __align__(16) unsigned short sB[256 * 64];   // 32 KiB

    const int tid = threadIdx.x;
    const int l   = tid & 63;
    const int w   = tid >> 6;
    const int wm  = w >> 1, wn = w & 1;
    const int q   = l >> 4;          // quad -> k-group within chunk
    const int cc  = l & 15;          // row/col lane
    const int row0 = blockIdx.x * 128;
    const int nb   = blockIdx.y * 1024;

    // chunk-invariant LDS byte offsets (hi granule; lo = ^16)
    int rdA[4], rdB[8];
#pragma unroll
    for (int t = 0; t < 4; ++t) {
        int ra = wm * 64 + t * 16 + cc;
        rdA[t] = ra * 128 + (((q << 1)) ^ (ra & 7)) * 16;
    }
#pragma unroll
    for (int t = 0; t < 8; ++t) {
        int rb = wn * 128 + t * 16 + cc;
        rdB[t] = rb * 128 + (((q << 1)) ^ (rb & 7)) * 16;
    }

    float v1[16], v2[16];
    unsigned pi1[8], pi2[8];
#pragma unroll
    for (int s = 0; s < 16; ++s) { v1[s] = 3.4028235e38f; v2[s] = 3.4028235e38f; }
#pragma unroll
    for (int s = 0; s < 8; ++s) { pi1[s] = 0u; pi2[s] = 0u; }

    for (int n0 = 0; n0 < 4; ++n0) {
        f32x4 acc[4][8];
#pragma unroll
        for (int tm = 0; tm < 4; ++tm)
#pragma unroll
            for (int tn = 0; tn < 8; ++tn) { f32x4 z = {0.f,0.f,0.f,0.f}; acc[tm][tn] = z; }

        for (int c = 0; c < NCH; ++c) {
            __syncthreads();   // prior chunk's readers done
            {
                size_t abase = ((size_t)c * BL + row0) * 64;
                size_t bbase = ((size_t)c * K + nb + n0 * 256) * 64;
#pragma unroll
                for (int i = 0; i < 12; ++i) {
                    int gi = i * 4 + w;          // 0..47: 16 A groups then 32 B groups
                    if (gi < 16)
                        load_lds16(xp + abase + gi * 512 + l * 8, &sA[gi * 512 + l * 8]);
                    else {
                        int gb = gi - 16;
                        load_lds16(cbp + bbase + gb * 512 + l * 8, &sB[gb * 512 + l * 8]);
                    }
                }
            }
            __syncthreads();   // DMA drained
            bf16x8 Ah[4], Al[4];
#pragma unroll
            for (int t = 0; t < 4; ++t) {
                Ah[t] = *(const bf16x8*)((const char*)sA + rdA[t]);
                Al[t] = *(const bf16x8*)((const char*)sA + (rdA[t] ^ 16));
            }
#pragma unroll
            for (int tn = 0; tn < 8; ++tn) {
                bf16x8 Bh = *(const bf16x8*)((const char*)sB + rdB[tn]);
                bf16x8 Bl = *(const bf16x8*)((const char*)sB + (rdB[tn] ^ 16));
#pragma unroll
                for (int tm = 0; tm < 4; ++tm) {
                    acc[tm][tn] = MFMA(Ah[tm], Bh, acc[tm][tn]);
                    acc[tm][tn] = MFMA(Ah[tm], Bl, acc[tm][tn]);
                    acc[tm][tn] = MFMA(Al[tm], Bh, acc[tm][tn]);
                }
            }
        }
        // epilogue: dd + running top-2 (C layout: col=lane&15, row=quad*4+reg)
        float c2v[8];
#pragma unroll
        for (int tn = 0; tn < 8; ++tn)
            c2v[tn] = c2[nb + n0 * 256 + wn * 128 + tn * 16 + cc];
#pragma unroll
        for (int tm = 0; tm < 4; ++tm)
#pragma unroll
            for (int r = 0; r < 4; ++r) {
                int s = tm * 4 + r;
                int sh = (s & 1) * 16;
                float x2v = x2[row0 + wm * 64 + tm * 16 + q * 4 + r];
                float vv1 = v1[s], vv2 = v2[s];
                unsigned i1s = (pi1[s >> 1] >> sh) & 0xFFFFu;
                unsigned i2s = (pi2[s >> 1] >> sh) & 0xFFFFu;
#pragma unroll
                for (int tn = 0; tn < 8; ++tn) {
                    unsigned col = nb + n0 * 256 + wn * 128 + tn * 16 + cc;
                    float dd = (x2v - 2.0f * acc[tm][tn][r]) + c2v[tn];
                    if (dd < vv1) { vv2 = vv1; i2s = i1s; vv1 = dd; i1s = col; }
                    else if (dd < vv2) { vv2 = dd; i2s = col; }
                }
                v1[s] = vv1; v2[s] = vv2;
                pi1[s >> 1] = (pi1[s >> 1] & ~(0xFFFFu << sh)) | (i1s << sh);
                pi2[s >> 1] = (pi2[s >> 1] & ~(0xFFFFu << sh)) | (i2s << sh);
            }
    }

    // merge: per slot, pack u64 keys, butterfly over 16 col-lanes, cross-wave via LDS
    __syncthreads();
    unsigned long long* sc = (unsigned long long*)sA;   // [128 rows][2 wn][2] = 4 KiB
#pragma unroll
    for (int s = 0; s < 16; ++s) {
        int sh = (s & 1) * 16;
        unsigned long long k1 =
            ((unsigned long long)__float_as_uint(v1[s]) << 12) |
            (unsigned long long)((pi1[s >> 1] >> sh) & 0xFFFu);
        unsigned long long k2 =
            ((unsigned long long)__float_as_uint(v2[s]) << 12) |
            (unsigned long long)((pi2[s >> 1] >> sh) & 0xFFFu);
#pragma unroll
        for (int m = 1; m < 16; m <<= 1) {
            unsigned long long o1 = __shfl_xor(k1, m, 64);
            unsigned long long o2 = __shfl_xor(k2, m, 64);
            unsigned long long lf = k1 > o1 ? k1 : o1;   // loser of firsts
            unsigned long long ws_ = k2 < o2 ? k2 : o2;  // winner of seconds
            k1 = k1 < o1 ? k1 : o1;
            k2 = lf < ws_ ? lf : ws_;
        }
        if (cc == 0) {
            int rl = wm * 64 + (s >> 2) * 16 + q * 4 + (s & 3);
            sc[(rl * 2 + wn) * 2 + 0] = k1;
            sc[(rl * 2 + wn) * 2 + 1] = k2;
        }
    }
    __syncthreads();
    if (tid < 128) {
        unsigned long long pa1 = sc[(tid * 2 + 0) * 2 + 0], pa2 = sc[(tid * 2 + 0) * 2 + 1];
        unsigned long long pb1 = sc[(tid * 2 + 1) * 2 + 0], pb2 = sc[(tid * 2 + 1) * 2 + 1];
        unsigned long long m1 = pa1 < pb1 ? pa1 : pb1;
        unsigned long long lf = pa1 > pb1 ? pa1 : pb1;
        unsigned long long ws_ = pa2 < pb2 ? pa2 : pb2;
        unsigned long long m2 = lf < ws_ ? lf : ws_;
        size_t base = (size_t)(row0 + tid) * 8 + blockIdx.y * 2;
        cand[base + 0] = (unsigned short)(m1 & 0xFFFULL);
        cand[base + 1] = (unsigned short)(m2 & 0xFFFULL);
    }
}

// ================= fallback argmin (round-1 verbatim, proven) ===============
__global__ __launch_bounds__(256) void argmin_fb(
    const float* __restrict__ x, const float* __restrict__ cb,
    const float* __restrict__ x2, const float* __restrict__ c2,
    unsigned long long* __restrict__ keys)
{
    __shared__ __align__(16) float As[32][68];
    __shared__ __align__(16) float Bs[32][68];
    __shared__ float rv[64][16];
    __shared__ int   ri[64][16];

    const int tid  = threadIdx.x;
    const int tx   = tid & 15;
    const int ty   = tid >> 4;
    const int row0 = blockIdx.x * 64;
    const int nb   = blockIdx.y * 1024;

    float x2r[4];
#pragma unroll
    for (int m = 0; m < 4; ++m) x2r[m] = x2[row0 + ty * 4 + m];

    float minv[4]; int mini[4];
#pragma unroll
    for (int m = 0; m < 4; ++m) { minv[m] = 3.4028235e38f; mini[m] = 0; }

    for (int n0 = 0; n0 < 1024; n0 += 64) {
        float acc[4][4];
#pragma unroll
        for (int m = 0; m < 4; ++m)
#pragma unroll
            for (int n = 0; n < 4; ++n) acc[m][n] = 0.f;

        for (int d0 = 0; d0 < D; d0 += 32) {
            __syncthreads();
#pragma unroll
            for (int j = 0; j < 2; ++j) {
                int v   = j * 256 + tid;
                int row = v >> 3;
                int col = (v & 7) * 4;
                float4 av = *(const float4*)(x  + (size_t)(row0 + row) * D + d0 + col);
                As[col + 0][row] = av.x; As[col + 1][row] = av.y;
                As[col + 2][row] = av.z; As[col + 3][row] = av.w;
                float4 bv = *(const float4*)(cb + (size_t)(nb + n0 + row) * D + d0 + col);
                Bs[col + 0][row] = bv.x; Bs[col + 1][row] = bv.y;
                Bs[col + 2][row] = bv.z; Bs[col + 3][row] = bv.w;
            }
            __syncthreads();
#pragma unroll
            for (int kk = 0; kk < 32; ++kk) {
                float4 a4 = *(const float4*)&As[kk][ty * 4];
                float4 b4 = *(const float4*)&Bs[kk][tx * 4];
                float a_[4] = { a4.x, a4.y, a4.z, a4.w };
                float b_[4] = { b4.x, b4.y, b4.z, b4.w };
#pragma unroll
                for (int m = 0; m < 4; ++m)
#pragma unroll
                    for (int n = 0; n < 4; ++n)
                        acc[m][n] = fmaf(a_[m], b_[n], acc[m][n]);
            }
        }
#pragma unroll
        for (int n = 0; n < 4; ++n) {
            int kidx = nb + n0 + tx * 4 + n;
            float c2k = c2[kidx];
#pragma unroll
            for (int m = 0; m < 4; ++m) {
                float wv = x2r[m] - 2.0f * acc[m][n];
                float dd = wv + c2k;
                if (dd < minv[m]) { minv[m] = dd; mini[m] = kidx; }
            }
        }
    }
#pragma unroll
    for (int m = 0; m < 4; ++m) { rv[ty * 4 + m][tx] = minv[m]; ri[ty * 4 + m][tx] = mini[m]; }
    __syncthreads();
    if (tid < 64) {
        float bv = rv[tid][0]; int bi = ri[tid][0];
#pragma unroll
        for (int j = 1; j < 16; ++j) {
            float v = rv[tid][j]; int ii = ri[tid][j];
            if (v < bv || (v == bv && ii < bi)) { bv = v; bi = ii; }
        }
        unsigned long long key =
            ((unsigned long long)__float_as_uint(bv) << 12) | (unsigned long long)bi;
        atomicMin(&keys[row0 + tid], key);
    }
}

// ================= downstream ==============================================

__global__ void count_kernel(const unsigned long long* __restrict__ keys,
                             float* __restrict__ counts, unsigned short* __restrict__ idx16)
{
    int i = blockIdx.x * 256 + threadIdx.x;
    int k = (int)(keys[i] & 0xFFFULL);
    idx16[i] = (unsigned short)k;
    atomicAdd(&counts[k], 1.0f);
}

__global__ __launch_bounds__(256) void ema_cluster_kernel(
    const float* __restrict__ hc, const float* __restrict__ counts,
    const float* __restrict__ countp, float* __restrict__ avgc, float* __restrict__ Nout)
{
    __shared__ float sm[256];
    int i = blockIdx.x * 256 + threadIdx.x;
    const float om = 1.0f - 0.99f;
    float bias = 1.0f - powf(0.99f, countp[0] + 1.0f);
    float a = (hc[i] * 0.99f + om * counts[i]) / bias;
    avgc[i] = a;
    sm[threadIdx.x] = a;
    __syncthreads();
    for (int s = 128; s > 0; s >>= 1) {
        if (threadIdx.x < s) sm[threadIdx.x] += sm[threadIdx.x + s];
        __syncthreads();
    }
    if (threadIdx.x == 0) atomicAdd(Nout, sm[0]);
}

// per-code gather of assigned x rows + EMA + codebook_new (scans compact u16 idx)
__global__ __launch_bounds__(256) void code_update_kernel(
    const float* __restrict__ x, const unsigned short* __restrict__ idx16,
    const float* __restrict__ hdw, const float* __restrict__ avgc,
    const float* __restrict__ Nptr, const float* __restrict__ countp,
    float* __restrict__ cbn)
{
    __shared__ unsigned short rows[2048];
    __shared__ int cnt;
    int k = blockIdx.x, tid = threadIdx.x;
    if (tid == 0) cnt = 0;
    __syncthreads();
    const uint4* ip = (const uint4*)idx16;   // 2048 x (8 u16)
    for (int j = 0; j < 8; ++j) {
        int u = j * 256 + tid;
        uint4 v = ip[u];
        unsigned ww[4] = {v.x, v.y, v.z, v.w};
#pragma unroll
        for (int e = 0; e < 4; ++e) {
            int k0 = (int)(ww[e] & 0xFFFFu), k1 = (int)(ww[e] >> 16);
            if (k0 == k) { int p = atomicAdd(&cnt, 1); if (p < 2048) rows[p] = (unsigned short)(u * 8 + e * 2); }
            if (k1 == k) { int p = atomicAdd(&cnt, 1); if (p < 2048) rows[p] = (unsigned short)(u * 8 + e * 2 + 1); }
        }
    }
    __syncthreads();
    int n = cnt < 2048 ? cnt : 2048;
    float a0 = 0.f, a1 = 0.f;
    for (int p = 0; p < n; ++p) {
        int r = rows[p];
        a0 += x[(size_t)r * D + tid];
        a1 += x[(size_t)r * D + tid + 256];
    }
    const float om = 1.0f - 0.99f;
    float bias = 1.0f - powf(0.99f, countp[0] + 1.0f);
    float Nv = *Nptr;
    float ccv = ((avgc[k] + 1e-5f) / (Nv + 0.04096f)) * Nv;
    size_t b = (size_t)k * D;
    cbn[b + tid]       = ((hdw[b + tid]       * 0.99f + om * a0) / bias) / ccv;
    cbn[b + tid + 256] = ((hdw[b + tid + 256] * 0.99f + om * a1) / bias) / ccv;
}

__global__ __launch_bounds__(256) void gather_kernel(
    const float* __restrict__ x, const unsigned long long* __restrict__ keys,
    const float* __restrict__ cbn, float* __restrict__ outq,
    float* __restrict__ partial)
{
    __shared__ float sm[256];
    int row = blockIdx.x;
    int tid = threadIdx.x;
    int k   = (int)(keys[row] & 0xFFFULL);
    const float* xpp = x   + (size_t)row * D;
    const float* cp  = cbn + (size_t)k   * D;
    float* op = outq + (size_t)row * D;
    float local = 0.f;
#pragma unroll
    for (int j = 0; j < 2; ++j) {
        int d = tid + j * 256;
        float xv = xpp[d];
        float qv = cp[d];
        float quant = xv + (qv - xv);
        op[d] = quant;
        float diff = xv - quant;
        local = fmaf(diff, diff, local);
    }
    sm[tid] = local;
    __syncthreads();
    for (int s = 128; s > 0; s >>= 1) {
        if (tid < s) sm[tid] += sm[tid + s];
        __syncthreads();
    }
    if (tid == 0) {
        partial[row] = sm[0];
        outq[8388609 + row] = (float)k;
    }
}

__global__ __launch_bounds__(256) void finalize_kernel(
    const float* __restrict__ partial, float* __restrict__ out)
{
    __shared__ double sm[256];
    int tid = threadIdx.x;
    double s = 0.0;
#pragma unroll
    for (int j = 0; j < 64; ++j) s += (double)partial[tid + j * 256];
    sm[tid] = s;
    __syncthreads();
    for (int st = 128; st > 0; st >>= 1) {
        if (tid < st) sm[tid] += sm[tid + st];
        __syncthreads();
    }
    if (tid == 0) out[8388608] = (float)(0.5 * sm[0] / 8388608.0);
}

// ================= launcher ================================================

extern "C" void kernel_launch(void* const* d_in, const int* in_sizes, int n_in,
                              void* d_out, int out_size, void* d_ws, size_t ws_size,
                              hipStream_t stream)
{
    const float* x   = (const float*)d_in[0];
    const float* cb  = (const float*)d_in[1];
    const float* hc  = (const float*)d_in[2];
    const float* hdw = (const float*)d_in[3];
    const float* cnt = (const float*)d_in[4];
    float* out = (float*)d_out;

    char* ws = (char*)d_ws;
    float*  c2     = (float*)(ws + OFF_C2);
    float*  x2     = (float*)(ws + OFF_X2);
    float*  counts = (float*)(ws + OFF_CNT);
    float*  avgc   = (float*)(ws + OFF_AVGC);
    float*  Nout   = (float*)(ws + OFF_SCAL + 8);
    unsigned short* idx16 = (unsigned short*)(ws + OFF_IDX16);
    unsigned long long* keys = (unsigned long long*)(ws + OFF_KEYS);
    float*  partial= (float*)(ws + OFF_X2);   // x2 dead after rescore

    hipMemsetAsync(ws + OFF_CNT, 0, (32 << 10) + 16, stream);

    rowsq_all<<<K + BL, 64, 0, stream>>>(x, cb, x2, c2);

    const bool primary = ws_size >= ((size_t)10 << 20);
    float* cbn;
    if (primary) {
        // x' stream = 16*16384*128 B = 33,554,432 B: exactly d_out's quantized
        // region (8388608 f); gather overwrites it at the end. cb' = 8.39 MB in ws.
        unsigned short* gxp = (unsigned short*)d_out;
        unsigned short* gcp = (unsigned short*)(ws + OFF_CBP);
        unsigned short* cand = (unsigned short*)(ws + OFF_CAND);
        cbn = (float*)(ws + OFF_CBP);   // reuses cb' after argmin

        split_interleave<<<10240, 256, 0, stream>>>(x, cb, gxp, gcp);
        argmin_mfma<<<dim3(BL / 128, 4), 256, 0, stream>>>(gxp, gcp, x2, c2, cand);
        rescore_kernel<<<(BL * 8) / 256, 256, 0, stream>>>(x, cb, x2, c2, cand, keys,
                                                           counts, idx16);
    } else {
        cbn = (float*)(ws + OFF_CBN_FB);
        hipMemsetAsync(ws + OFF_KEYS, 0xFF, BL * 8, stream);
        argmin_fb<<<dim3(BL / 64, 4), 256, 0, stream>>>(x, cb, x2, c2, keys);
        count_kernel<<<BL / 256, 256, 0, stream>>>(keys, counts, idx16);
    }

    ema_cluster_kernel<<<K / 256, 256, 0, stream>>>(hc, counts, cnt, avgc, Nout);
    code_update_kernel<<<K, 256, 0, stream>>>(x, idx16, hdw, avgc, Nout, cnt, cbn);
    gather_kernel<<<BL, 256, 0, stream>>>(x, keys, cbn, out, partial);
    finalize_kernel<<<1, 256, 0, stream>>>(partial, out);
}

// Round 7
// 334.159 us; speedup vs baseline: 1.1312x; 1.1312x over previous
//
#include <hip/hip_runtime.h>
#include <math.h>

#define BL 16384
#define D  512
#define K  4096
#define NCHB 8          // 64-k chunks: 512 k / 64
#define XLOFF 8388608   // halves offset of xl' stream inside d_out region

// ---- ws layout (bytes) ----
#define OFF_C2    0                // 4096 f
#define OFF_X2    (16<<10)         // 16384 f (aliased as loss partials after rescore)
#define OFF_CNT   (80<<10)         // 4096 f
#define OFF_AVGC  (96<<10)         // 4096 f
#define OFF_SCAL  (112<<10)        // N float @+8
#define OFF_IDX16 (116<<10)        // 16384 u16
#define OFF_KEYS  (160<<10)        // 16384 u64
#define OFF_CAND  (288<<10)        // 16384*8 u16
#define OFF_CBP   (576<<10)        // cb' 8*4096*128 B = 4.19 MB; cbn (8 MB) reuses after argmin
#define OFF_CBN_FB (256<<10)       // fallback cbn

typedef _Float16 f16x8 __attribute__((ext_vector_type(8)));
typedef float    f32x4 __attribute__((ext_vector_type(4)));
#define MFMA16(a,b,c) __builtin_amdgcn_mfma_f32_16x16x32_f16(a,b,c,0,0,0)

// ================= bit-exact helpers (feed exact rescore — DO NOT TOUCH) ====

__global__ void rowsq_all(const float* __restrict__ x, const float* __restrict__ cb,
                          float* __restrict__ x2, float* __restrict__ c2)
{
    int b    = blockIdx.x;
    int lane = threadIdx.x;              // 64
    const float* p; float* o; int row;
    if (b < K) { p = cb; o = c2; row = b; }
    else       { p = x;  o = x2; row = b - K; }
    p += (size_t)row * D;
    float s = 0.f;
#pragma unroll
    for (int j = 0; j < D / 64; ++j) {
        float v = p[lane + j * 64];
        s = fmaf(v, v, s);
    }
#pragma unroll
    for (int off = 32; off > 0; off >>= 1)
        s += __shfl_down(s, off, 64);
    if (lane == 0) o[row] = s;
}

// exact rescore, bit-identical arithmetic to round-1 (sequential fmaf k=0..511);
// also emits counts + compact u16 indices.
__global__ __launch_bounds__(256) void rescore_kernel(
    const float* __restrict__ x, const float* __restrict__ cb,
    const float* __restrict__ x2, const float* __restrict__ c2,
    const unsigned short* __restrict__ cand,
    unsigned long long* __restrict__ keys,
    float* __restrict__ counts, unsigned short* __restrict__ idx16)
{
    int t = blockIdx.x * 256 + threadIdx.x;  // 131072
    int row = t >> 3, ci = t & 7;
    int idx = cand[(size_t)row * 8 + ci];
    const float* xp = x  + (size_t)row * D;
    const float* cp = cb + (size_t)idx * D;
    float acc = 0.f;
#pragma unroll 4
    for (int k0 = 0; k0 < D; k0 += 4) {
        float4 xv = *(const float4*)(xp + k0);
        float4 cv = *(const float4*)(cp + k0);
        acc = fmaf(xv.x, cv.x, acc);
        acc = fmaf(xv.y, cv.y, acc);
        acc = fmaf(xv.z, cv.z, acc);
        acc = fmaf(xv.w, cv.w, acc);
    }
    float wv = x2[row] - 2.0f * acc;
    float dd = wv + c2[idx];
    unsigned long long key =
        ((unsigned long long)__float_as_uint(dd) << 12) | (unsigned long long)idx;
#pragma unroll
    for (int m = 1; m < 8; m <<= 1) {
        unsigned long long o = __shfl_xor(key, m, 64);
        key = o < key ? o : key;
    }
    if ((t & 7) == 0) {
        keys[row] = key;
        int kf = (int)(key & 0xFFFULL);
        idx16[row] = (unsigned short)kf;
        atomicAdd(&counts[kf], 1.0f);
    }
}

// ================= primary path ============================================

__device__ __forceinline__ void load_lds16(const unsigned short* g, unsigned short* l) {
    __builtin_amdgcn_global_load_lds(
        (const __attribute__((address_space(1))) unsigned int*)(g),
        (__attribute__((address_space(3))) unsigned int*)(l), 16, 0, 0);
}

// fp32 -> fp16 hi/lo streams. 64-k chunks, 128 B rows, 8 granules x 16 B,
// phys granule p = g ^ (row&7) (g = k-group 0..7, k = 64c + 8g .. +7).
// x: hi stream at xp[0..], lo stream at xp[XLOFF..]. cb: hi only.
__global__ __launch_bounds__(256) void split_interleave(
    const float* __restrict__ x, const float* __restrict__ cb,
    unsigned short* __restrict__ xp, unsigned short* __restrict__ cbp)
{
    int gw   = blockIdx.x * 4 + (threadIdx.x >> 6);  // 0..20479
    int lane = threadIdx.x & 63;
    int rl   = lane >> 3;
    int p    = lane & 7;
    const float* src; int nr, c, r0; bool isX;
    if (gw < 16384) { c = gw >> 11; r0 = (gw & 2047) * 8; src = x;  nr = BL; isX = true; }
    else { int lw = gw - 16384; c = lw >> 9; r0 = (lw & 511) * 8; src = cb; nr = K; isX = false; }
    int r = r0 + rl;
    int g = p ^ rl;                  // r&7 == rl
    const float* sp = src + (size_t)r * D + c * 64 + g * 8;
    float4 f0 = *(const float4*)sp, f1 = *(const float4*)(sp + 4);
    float f[8] = {f0.x,f0.y,f0.z,f0.w,f1.x,f1.y,f1.z,f1.w};
    __align__(16) _Float16 oh[8], ol[8];
#pragma unroll
    for (int i = 0; i < 8; ++i) {
        _Float16 h = (_Float16)f[i];           // RNE
        oh[i] = h;
        ol[i] = (_Float16)(f[i] - (float)h);   // exact residual -> RNE fp16
    }
    size_t off = ((size_t)(c * nr + r) * 8 + p) * 8;   // halves
    if (isX) {
        *(uint4*)(xp + off)         = *(const uint4*)oh;
        *(uint4*)(xp + XLOFF + off) = *(const uint4*)ol;
    } else {
        *(uint4*)(cbp + off) = *(const uint4*)oh;
    }
}

// MFMA approx distance + per-split top-2.  f16 2-product: (xh+xl)*ch.
// Block 128 rows x 128 codes, 4 waves (2x2), wave tile 64x64 = 4x4 of 16x16x32 f16.
// Per 64-k chunk: 24 ds_read_b128 feed 64 MFMAs. DMA staging, XOR-swizzled LDS.
__global__ __launch_bounds__(256, 2) void argmin_mfma(
    const unsigned short* __restrict__ xp, const unsigned short* __restrict__ cbp,
    const float* __restrict__ x2, const float* __restrict__ c2,
    unsigned short* __restrict__ cand)
{
    __shared__ __align__(16) unsigned short sAh[128 * 64];   // 16 KiB
    __shared__ __align__(16) unsigned short sAl[128 * 64];   // 16 KiB
    __shared__ __align__(16) unsigned short sB [128 * 64];   // 16 KiB

    const int tid = threadIdx.x;
    const int l   = tid & 63;
    const int w   = tid >> 6;
    const int wm  = w >> 1, wn = w & 1;
    const int q   = l >> 4;          // quad -> k-subgroup
    const int cc  = l & 15;          // row/col lane
    const int row0 = blockIdx.x * 128;
    const int nb   = blockIdx.y * 1024;

    // chunk-invariant LDS byte offsets for kh=0 (g=q); kh=1 -> ^64 (g=q+4)
    int rdA[4], rdB[4];
#pragma unroll
    for (int t = 0; t < 4; ++t) {
        int ra = wm * 64 + t * 16 + cc;
        int rb = wn * 64 + t * 16 + cc;
        rdA[t] = ra * 128 + ((q ^ (ra & 7)) * 16);
        rdB[t] = rb * 128 + ((q ^ (rb & 7)) * 16);
    }

    unsigned long long k1[16], k2[16];
#pragma unroll
    for (int s = 0; s < 16; ++s) { k1[s] = ~0ULL; k2[s] = ~0ULL; }

    for (int n0 = 0; n0 < 8; ++n0) {
        f32x4 acc[4][4];
#pragma unroll
        for (int tm = 0; tm < 4; ++tm)
#pragma unroll
            for (int tn = 0; tn < 4; ++tn) { f32x4 z = {0.f,0.f,0.f,0.f}; acc[tm][tn] = z; }

        for (int c = 0; c < NCHB; ++c) {
            __syncthreads();   // prior chunk's readers done
            {
                size_t abase = ((size_t)c * BL + row0) * 64;
                size_t bbase = ((size_t)c * K + nb + n0 * 128) * 64;
#pragma unroll
                for (int i = 0; i < 12; ++i) {
                    int gi = i * 4 + w;          // 0..47 (wave-uniform)
                    if (gi < 16)
                        load_lds16(xp + abase + gi * 512 + l * 8, &sAh[gi * 512 + l * 8]);
                    else if (gi < 32) {
                        int ga = gi - 16;
                        load_lds16(xp + XLOFF + abase + ga * 512 + l * 8, &sAl[ga * 512 + l * 8]);
                    } else {
                        int gb = gi - 32;
                        load_lds16(cbp + bbase + gb * 512 + l * 8, &sB[gb * 512 + l * 8]);
                    }
                }
            }
            __syncthreads();   // DMA drained
#pragma unroll
            for (int kh = 0; kh < 2; ++kh) {
                const int xo = kh * 64;
                f16x8 Ah[4], Al[4], Bf[4];
#pragma unroll
                for (int t = 0; t < 4; ++t) {
                    Ah[t] = *(const f16x8*)((const char*)sAh + (rdA[t] ^ xo));
                    Al[t] = *(const f16x8*)((const char*)sAl + (rdA[t] ^ xo));
                    Bf[t] = *(const f16x8*)((const char*)sB  + (rdB[t] ^ xo));
                }
#pragma unroll
                for (int tm = 0; tm < 4; ++tm)
#pragma unroll
                    for (int tn = 0; tn < 4; ++tn) {
                        acc[tm][tn] = MFMA16(Ah[tm], Bf[tn], acc[tm][tn]);
                        acc[tm][tn] = MFMA16(Al[tm], Bf[tn], acc[tm][tn]);
                    }
            }
        }
        // epilogue: dd + running top-2 (C layout: col=lane&15, row=quad*4+reg)
        float c2v[4];
#pragma unroll
        for (int tn = 0; tn < 4; ++tn)
            c2v[tn] = c2[nb + n0 * 128 + wn * 64 + tn * 16 + cc];
#pragma unroll
        for (int tm = 0; tm < 4; ++tm)
#pragma unroll
            for (int r = 0; r < 4; ++r) {
                int s = tm * 4 + r;
                float x2v = x2[row0 + wm * 64 + tm * 16 + q * 4 + r];
#pragma unroll
                for (int tn = 0; tn < 4; ++tn) {
                    unsigned col = nb + n0 * 128 + wn * 64 + tn * 16 + cc;
                    float dd = (x2v - 2.0f * acc[tm][tn][r]) + c2v[tn];
                    unsigned long long key =
                        ((unsigned long long)__float_as_uint(dd) << 12) | col;
                    if (key < k1[s]) { k2[s] = k1[s]; k1[s] = key; }
                    else if (key < k2[s]) { k2[s] = key; }
                }
            }
    }

    // butterfly top-2 merge across the 16 col-lanes (quads keep their rows)
#pragma unroll
    for (int s = 0; s < 16; ++s) {
#pragma unroll
        for (int m = 1; m < 16; m <<= 1) {
            unsigned long long o1 = __shfl_xor(k1[s], m, 64);
            unsigned long long o2 = __shfl_xor(k2[s], m, 64);
            unsigned long long lf = k1[s] > o1 ? k1[s] : o1;   // loser of firsts
            unsigned long long ws_ = k2[s] < o2 ? k2[s] : o2;  // winner of seconds
            k1[s] = k1[s] < o1 ? k1[s] : o1;
            k2[s] = lf < ws_ ? lf : ws_;
        }
    }

    // cross-wave (wn) merge via LDS, then candidate write
    __syncthreads();
    unsigned long long* sc = (unsigned long long*)sAh;   // [128 rows][2 wn][2] = 4 KiB
    if (cc == 0) {
#pragma unroll
        for (int s = 0; s < 16; ++s) {
            int rl = wm * 64 + (s >> 2) * 16 + q * 4 + (s & 3);
            sc[(rl * 2 + wn) * 2 + 0] = k1[s];
            sc[(rl * 2 + wn) * 2 + 1] = k2[s];
        }
    }
    __syncthreads();
    if (tid < 128) {
        unsigned long long pa1 = sc[(tid * 2 + 0) * 2 + 0], pa2 = sc[(tid * 2 + 0) * 2 + 1];
        unsigned long long pb1 = sc[(tid * 2 + 1) * 2 + 0], pb2 = sc[(tid * 2 + 1) * 2 + 1];
        unsigned long long m1 = pa1 < pb1 ? pa1 : pb1;
        unsigned long long lf = pa1 > pb1 ? pa1 : pb1;
        unsigned long long ws_ = pa2 < pb2 ? pa2 : pb2;
        unsigned long long m2 = lf < ws_ ? lf : ws_;
        size_t base = (size_t)(row0 + tid) * 8 + blockIdx.y * 2;
        cand[base + 0] = (unsigned short)(m1 & 0xFFFULL);
        cand[base + 1] = (unsigned short)(m2 & 0xFFFULL);
    }
}

// ================= fallback argmin (round-1 verbatim, proven) ===============
__global__ __launch_bounds__(256) void argmin_fb(
    const float* __restrict__ x, const float* __restrict__ cb,
    const float* __restrict__ x2, const float* __restrict__ c2,
    unsigned long long* __restrict__ keys)
{
    __shared__ __align__(16) float As[32][68];
    __shared__ __align__(16) float Bs[32][68];
    __shared__ float rv[64][16];
    __shared__ int   ri[64][16];

    const int tid  = threadIdx.x;
    const int tx   = tid & 15;
    const int ty   = tid >> 4;
    const int row0 = blockIdx.x * 64;
    const int nb   = blockIdx.y * 1024;

    float x2r[4];
#pragma unroll
    for (int m = 0; m < 4; ++m) x2r[m] = x2[row0 + ty * 4 + m];

    float minv[4]; int mini[4];
#pragma unroll
    for (int m = 0; m < 4; ++m) { minv[m] = 3.4028235e38f; mini[m] = 0; }

    for (int n0 = 0; n0 < 1024; n0 += 64) {
        float acc[4][4];
#pragma unroll
        for (int m = 0; m < 4; ++m)
#pragma unroll
            for (int n = 0; n < 4; ++n) acc[m][n] = 0.f;

        for (int d0 = 0; d0 < D; d0 += 32) {
            __syncthreads();
#pragma unroll
            for (int j = 0; j < 2; ++j) {
                int v   = j * 256 + tid;
                int row = v >> 3;
                int col = (v & 7) * 4;
                float4 av = *(const float4*)(x  + (size_t)(row0 + row) * D + d0 + col);
                As[col + 0][row] = av.x; As[col + 1][row] = av.y;
                As[col + 2][row] = av.z; As[col + 3][row] = av.w;
                float4 bv = *(const float4*)(cb + (size_t)(nb + n0 + row) * D + d0 + col);
                Bs[col + 0][row] = bv.x; Bs[col + 1][row] = bv.y;
                Bs[col + 2][row] = bv.z; Bs[col + 3][row] = bv.w;
            }
            __syncthreads();
#pragma unroll
            for (int kk = 0; kk < 32; ++kk) {
                float4 a4 = *(const float4*)&As[kk][ty * 4];
                float4 b4 = *(const float4*)&Bs[kk][tx * 4];
                float a_[4] = { a4.x, a4.y, a4.z, a4.w };
                float b_[4] = { b4.x, b4.y, b4.z, b4.w };
#pragma unroll
                for (int m = 0; m < 4; ++m)
#pragma unroll
                    for (int n = 0; n < 4; ++n)
                        acc[m][n] = fmaf(a_[m], b_[n], acc[m][n]);
            }
        }
#pragma unroll
        for (int n = 0; n < 4; ++n) {
            int kidx = nb + n0 + tx * 4 + n;
            float c2k = c2[kidx];
#pragma unroll
            for (int m = 0; m < 4; ++m) {
                float wv = x2r[m] - 2.0f * acc[m][n];
                float dd = wv + c2k;
                if (dd < minv[m]) { minv[m] = dd; mini[m] = kidx; }
            }
        }
    }
#pragma unroll
    for (int m = 0; m < 4; ++m) { rv[ty * 4 + m][tx] = minv[m]; ri[ty * 4 + m][tx] = mini[m]; }
    __syncthreads();
    if (tid < 64) {
        float bv = rv[tid][0]; int bi = ri[tid][0];
#pragma unroll
        for (int j = 1; j < 16; ++j) {
            float v = rv[tid][j]; int ii = ri[tid][j];
            if (v < bv || (v == bv && ii < bi)) { bv = v; bi = ii; }
        }
        unsigned long long key =
            ((unsigned long long)__float_as_uint(bv) << 12) | (unsigned long long)bi;
        atomicMin(&keys[row0 + tid], key);
    }
}

// ================= downstream ==============================================

__global__ void count_kernel(const unsigned long long* __restrict__ keys,
                             float* __restrict__ counts, unsigned short* __restrict__ idx16)
{
    int i = blockIdx.x * 256 + threadIdx.x;
    int k = (int)(keys[i] & 0xFFFULL);
    idx16[i] = (unsigned short)k;
    atomicAdd(&counts[k], 1.0f);
}

__global__ __launch_bounds__(256) void ema_cluster_kernel(
    const float* __restrict__ hc, const float* __restrict__ counts,
    const float* __restrict__ countp, float* __restrict__ avgc, float* __restrict__ Nout)
{
    __shared__ float sm[256];
    int i = blockIdx.x * 256 + threadIdx.x;
    const float om = 1.0f - 0.99f;
    float bias = 1.0f - powf(0.99f, countp[0] + 1.0f);
    float a = (hc[i] * 0.99f + om * counts[i]) / bias;
    avgc[i] = a;
    sm[threadIdx.x] = a;
    __syncthreads();
    for (int s = 128; s > 0; s >>= 1) {
        if (threadIdx.x < s) sm[threadIdx.x] += sm[threadIdx.x + s];
        __syncthreads();
    }
    if (threadIdx.x == 0) atomicAdd(Nout, sm[0]);
}

// per-code gather of assigned x rows + EMA + codebook_new (scans compact u16 idx)
__global__ __launch_bounds__(256) void code_update_kernel(
    const float* __restrict__ x, const unsigned short* __restrict__ idx16,
    const float* __restrict__ hdw, const float* __restrict__ avgc,
    const float* __restrict__ Nptr, const float* __restrict__ countp,
    float* __restrict__ cbn)
{
    __shared__ unsigned short rows[2048];
    __shared__ int cnt;
    int k = blockIdx.x, tid = threadIdx.x;
    if (tid == 0) cnt = 0;
    __syncthreads();
    const uint4* ip = (const uint4*)idx16;   // 2048 x (8 u16)
    for (int j = 0; j < 8; ++j) {
        int u = j * 256 + tid;
        uint4 v = ip[u];
        unsigned ww[4] = {v.x, v.y, v.z, v.w};
#pragma unroll
        for (int e = 0; e < 4; ++e) {
            int k0 = (int)(ww[e] & 0xFFFFu), k1 = (int)(ww[e] >> 16);
            if (k0 == k) { int p = atomicAdd(&cnt, 1); if (p < 2048) rows[p] = (unsigned short)(u * 8 + e * 2); }
            if (k1 == k) { int p = atomicAdd(&cnt, 1); if (p < 2048) rows[p] = (unsigned short)(u * 8 + e * 2 + 1); }
        }
    }
    __syncthreads();
    int n = cnt < 2048 ? cnt : 2048;
    float a0 = 0.f, a1 = 0.f;
    for (int p = 0; p < n; ++p) {
        int r = rows[p];
        a0 += x[(size_t)r * D + tid];
        a1 += x[(size_t)r * D + tid + 256];
    }
    const float om = 1.0f - 0.99f;
    float bias = 1.0f - powf(0.99f, countp[0] + 1.0f);
    float Nv = *Nptr;
    float ccv = ((avgc[k] + 1e-5f) / (Nv + 0.04096f)) * Nv;
    size_t b = (size_t)k * D;
    cbn[b + tid]       = ((hdw[b + tid]       * 0.99f + om * a0) / bias) / ccv;
    cbn[b + tid + 256] = ((hdw[b + tid + 256] * 0.99f + om * a1) / bias) / ccv;
}

__global__ __launch_bounds__(256) void gather_kernel(
    const float* __restrict__ x, const unsigned long long* __restrict__ keys,
    const float* __restrict__ cbn, float* __restrict__ outq,
    float* __restrict__ partial)
{
    __shared__ float sm[256];
    int row = blockIdx.x;
    int tid = threadIdx.x;
    int k   = (int)(keys[row] & 0xFFFULL);
    const float* xpp = x   + (size_t)row * D;
    const float* cp  = cbn + (size_t)k   * D;
    float* op = outq + (size_t)row * D;
    float local = 0.f;
#pragma unroll
    for (int j = 0; j < 2; ++j) {
        int d = tid + j * 256;
        float xv = xpp[d];
        float qv = cp[d];
        float quant = xv + (qv - xv);
        op[d] = quant;
        float diff = xv - quant;
        local = fmaf(diff, diff, local);
    }
    sm[tid] = local;
    __syncthreads();
    for (int s = 128; s > 0; s >>= 1) {
        if (tid < s) sm[tid] += sm[tid + s];
        __syncthreads();
    }
    if (tid == 0) {
        partial[row] = sm[0];
        outq[8388609 + row] = (float)k;
    }
}

__global__ __launch_bounds__(256) void finalize_kernel(
    const float* __restrict__ partial, float* __restrict__ out)
{
    __shared__ double sm[256];
    int tid = threadIdx.x;
    double s = 0.0;
#pragma unroll
    for (int j = 0; j < 64; ++j) s += (double)partial[tid + j * 256];
    sm[tid] = s;
    __syncthreads();
    for (int st = 128; st > 0; st >>= 1) {
        if (tid < st) sm[tid] += sm[tid + st];
        __syncthreads();
    }
    if (tid == 0) out[8388608] = (float)(0.5 * sm[0] / 8388608.0);
}

// ================= launcher ================================================

extern "C" void kernel_launch(void* const* d_in, const int* in_sizes, int n_in,
                              void* d_out, int out_size, void* d_ws, size_t ws_size,
                              hipStream_t stream)
{
    const float* x   = (const float*)d_in[0];
    const float* cb  = (const float*)d_in[1];
    const float* hc  = (const float*)d_in[2];
    const float* hdw = (const float*)d_in[3];
    const float* cnt = (const float*)d_in[4];
    float* out = (float*)d_out;

    char* ws = (char*)d_ws;
    float*  c2     = (float*)(ws + OFF_C2);
    float*  x2     = (float*)(ws + OFF_X2);
    float*  counts = (float*)(ws + OFF_CNT);
    float*  avgc   = (float*)(ws + OFF_AVGC);
    float*  Nout   = (float*)(ws + OFF_SCAL + 8);
    unsigned short* idx16 = (unsigned short*)(ws + OFF_IDX16);
    unsigned long long* keys = (unsigned long long*)(ws + OFF_KEYS);
    float*  partial= (float*)(ws + OFF_X2);   // x2 dead after rescore

    hipMemsetAsync(ws + OFF_CNT, 0, (32 << 10) + 16, stream);

    rowsq_all<<<K + BL, 64, 0, stream>>>(x, cb, x2, c2);

    const bool primary = ws_size >= ((size_t)10 << 20);
    float* cbn;
    if (primary) {
        // xh'+xl' streams = 2*8*16384*128 B = 33,554,432 B: exactly d_out's
        // quantized region; gather overwrites at the end. cb' (hi) = 4.19 MB in ws.
        unsigned short* gxp = (unsigned short*)d_out;
        unsigned short* gcp = (unsigned short*)(ws + OFF_CBP);
        unsigned short* cand = (unsigned short*)(ws + OFF_CAND);
        cbn = (float*)(ws + OFF_CBP);   // reuses cb' after argmin

        split_interleave<<<5120, 256, 0, stream>>>(x, cb, gxp, gcp);
        argmin_mfma<<<dim3(BL / 128, 4), 256, 0, stream>>>(gxp, gcp, x2, c2, cand);
        rescore_kernel<<<(BL * 8) / 256, 256, 0, stream>>>(x, cb, x2, c2, cand, keys,
                                                           counts, idx16);
    } else {
        cbn = (float*)(ws + OFF_CBN_FB);
        hipMemsetAsync(ws + OFF_KEYS, 0xFF, BL * 8, stream);
        argmin_fb<<<dim3(BL / 64, 4), 256, 0, stream>>>(x, cb, x2, c2, keys);
        count_kernel<<<BL / 256, 256, 0, stream>>>(keys, counts, idx16);
    }

    ema_cluster_kernel<<<K / 256, 256, 0, stream>>>(hc, counts, cnt, avgc, Nout);
    code_update_kernel<<<K, 256, 0, stream>>>(x, idx16, hdw, avgc, Nout, cnt, cbn);
    gather_kernel<<<BL, 256, 0, stream>>>(x, keys, cbn, out, partial);
    finalize_kernel<<<1, 256, 0, stream>>>(partial, out);
}